// Round 14
// baseline (335.800 us; speedup 1.0000x reference)
//
#include <hip/hip_runtime.h>
#include <math.h>

// Problem constants
#define B_   16
#define T_   64
#define N_   22
#define D_   64
#define K_   4
#define E_   8
#define H_   64
#define TW   59                 // valid time steps per batch (t=2..60 absolute)
#define M_   (B_ * TW)          // 944
#define NE_  (N_ * E_)          // 176
#define GRID (NE_ * 8)          // 1408
#define NDXT (N_ * D_)          // 1408
#define XTOT (B_ * T_ * N_ * D_)   // 1,441,792
#define NF4  (XTOT / 4)            // 360,448 float4s

typedef __attribute__((ext_vector_type(8))) short short8;
typedef __attribute__((ext_vector_type(4))) float float4v;

// workspace layout
#define ERRWS_BYTES  ((size_t)(M_ * N_ * E_) * 4)          // 664,576
#define XH_OFF       (ERRWS_BYTES)

// round-to-nearest bf16 (with tie bit): unbiased.
__device__ inline unsigned rtn_bf16(float f) {
    unsigned u = __float_as_uint(f);
    return (u + 0x7fffu + ((u >> 16) & 1u)) >> 16;
}

// ---------------------------------------------------------------------------
// Dispatch 1: blocks 0..127 = exact fp32 fix for the 128 expert_idx cells
// (b=g>>3, e=g&7 at t=TW-1, n=N-1); blocks 128..1407 = x -> bf16 RTN image;
// block 0 zeroes out[0] (for reduce's atomicAdd). [R13-proven code]
__global__ __launch_bounds__(256) void pre_kernel(
    const float* __restrict__ x, const int* __restrict__ nb,
    const float* __restrict__ W1, const float* __restrict__ b1,
    const float* __restrict__ W2, const float* __restrict__ b2,
    const float* __restrict__ W3, const float* __restrict__ b3,
    float* __restrict__ err_ws, short* __restrict__ xh,
    float* __restrict__ out)
{
    const int g   = blockIdx.x;
    const int tid = threadIdx.x;
    __shared__ __align__(16) char smem[6656];

    if (g < 128) {
        const int b = g >> 3;
        const int e = g & 7;
        const int n = N_ - 1, t = TW - 1;
        const int ne = n * E_ + e;
        const int j = tid & 63;
        const int q = tid >> 6;   // 0..3 K-quarter

        float* fbuf = (float*)smem;                      // 5120 B
        float (*part)[64] = (float(*)[64])(smem + 5120); // 1024 B
        float* h1s = (float*)(smem + 6144);              // 256 B
        float* h2s = (float*)(smem + 6400);              // 256 B

        if (g == 0 && tid == 0) out[0] = 0.f;

        for (int i = tid; i < 1280; i += 256) {
            int dt = i >> 8, r = i & 255;
            int k = r >> 6, d = r & 63;
            int nk = nb[n * K_ + k];
            fbuf[i] = x[(((size_t)(b * T_ + t + dt)) * N_ + nk) * D_ + d];
        }
        __syncthreads();

        const float* W1p = W1 + (size_t)ne * 1280 * 64;
        float s = 0.f;
        #pragma unroll 8
        for (int k = q * 320; k < q * 320 + 320; ++k) s += fbuf[k] * W1p[(size_t)k * 64 + j];
        part[q][j] = s;
        __syncthreads();
        if (q == 0)
            h1s[j] = fmaxf(part[0][j] + part[1][j] + part[2][j] + part[3][j]
                           + b1[(size_t)ne * H_ + j], 0.f);
        __syncthreads();

        const float* W2p = W2 + (size_t)ne * 4096;
        s = 0.f;
        #pragma unroll
        for (int k = q * 16; k < q * 16 + 16; ++k) s += h1s[k] * W2p[k * 64 + j];
        part[q][j] = s;
        __syncthreads();
        if (q == 0)
            h2s[j] = fmaxf(part[0][j] + part[1][j] + part[2][j] + part[3][j]
                           + b2[(size_t)ne * H_ + j], 0.f);
        __syncthreads();

        const float* W3p = W3 + (size_t)ne * 4096;
        s = 0.f;
        #pragma unroll
        for (int k = q * 16; k < q * 16 + 16; ++k) s += h2s[k] * W3p[k * 64 + j];
        part[q][j] = s;
        __syncthreads();
        if (q == 0) {
            float pred = part[0][j] + part[1][j] + part[2][j] + part[3][j]
                       + b3[(size_t)ne * D_ + j];
            float y = x[(((size_t)(b * T_ + t + 2)) * N_ + n) * D_ + j];
            float d = pred - y;
            float sq = d * d;
            sq += __shfl_xor(sq, 1);
            sq += __shfl_xor(sq, 2);
            sq += __shfl_xor(sq, 4);
            sq += __shfl_xor(sq, 8);
            sq += __shfl_xor(sq, 16);
            sq += __shfl_xor(sq, 32);
            if (j == 0) {
                int m = b * TW + t;
                err_ws[((size_t)m * N_ + n) * E_ + e] = sq * (1.f / 64.f);
            }
        }
    } else {
        int base = (g - 128) * 256 + tid;
        #pragma unroll
        for (int it = 0; it < 2; ++it) {
            int i = base + it * (1280 * 256);
            if (i < NF4) {
                float4 v = *(const float4*)(x + (size_t)i * 4);
                uint2 hp;
                hp.x = rtn_bf16(v.x) | (rtn_bf16(v.y) << 16);
                hp.y = rtn_bf16(v.z) | (rtn_bf16(v.w) << 16);
                *(uint2*)(xh + (size_t)i * 4) = hp;
            }
        }
    }
}

// ---------------------------------------------------------------------------
// Dispatch 2: GEMM, R11's exact 97 us body. __launch_bounds__(256,6):
// 6 blocks/CU (LDS 26,624 x 6 = 159.7 KB; VGPR 64 <= 85 cap) -> grid 1408
// fits in ONE dispatch round (capacity 1536) -- kills R11's 40% grid tail.
// Epilogue skips the 128 pre-computed fix cells (race-free vs dispatch 1).
__global__ __launch_bounds__(256, 6) void moe_err_kernel(
    const float* __restrict__ x, const short* __restrict__ xh,
    const int* __restrict__ nb,
    const float* __restrict__ W1, const float* __restrict__ W2,
    const float* __restrict__ W3,
    const float* __restrict__ b1, const float* __restrict__ b2,
    const float* __restrict__ b3, float* __restrict__ err_ws)
{
    const int tid = threadIdx.x;
    const int w   = tid >> 6;
    const int L   = tid & 63;
    const int g   = blockIdx.x;
    const int e   = g & 7;            // XCD = e
    const int mt  = (g >> 3) & 7;
    const int n   = g >> 6;
    const int ne  = n * E_ + e;

    __shared__ __align__(16) char smem[26624];
    char*  wbuf = smem;                       // 8 KB: 8 W images x 1 KB
    short* himg = (short*)(smem + 8192);      // 18,432 B: 128 x 72 shorts

    const int lrow = L & 15;
    const int dseg = (L >> 4) * 8;
    const int ccol = L & 15;
    const int qrow = (L >> 4) * 4;
    const int rowbase = mt * 128 + w * 32;

    const short* xhrow[2];
    #pragma unroll
    for (int rt = 0; rt < 2; ++rt) {
        int m  = rowbase + rt * 16 + lrow;
        int mc = m < M_ ? m : M_ - 1;
        int b = mc / TW, t = mc % TW;
        xhrow[rt] = xh + (size_t)(b * T_ + t) * NDXT;
    }

    const int o0 = __builtin_amdgcn_readfirstlane(nb[n * K_ + 0]) * D_;
    const int o1 = __builtin_amdgcn_readfirstlane(nb[n * K_ + 1]) * D_;
    const int o2 = __builtin_amdgcn_readfirstlane(nb[n * K_ + 2]) * D_;
    const int o3 = __builtin_amdgcn_readfirstlane(nb[n * K_ + 3]) * D_;

    const float* W1ne = W1 + (size_t)ne * (1280 * 64);
    const float* W2ne = W2 + (size_t)ne * 4096;
    const float* W3ne = W3 + (size_t)ne * 4096;
    auto csrc = [&](int c) {
        return c < 20 ? (W1ne + (size_t)c * 4096) : (c == 20 ? W2ne : W3ne);
    };

    // ---- W pipeline: 2-deep register prefetch; wave w owns images 2w,2w+1 ----
    float wf[2][2][8];
    uint4 wph[2];
    auto loadWf = [&](int wb, const float* src) {
        #pragma unroll
        for (int p = 0; p < 2; ++p) {
            const int pi = 2 * w + p;
            const float* sp = src + ((pi >> 2) * 32 + (L >> 4) * 8) * 64
                                  + ((pi & 3) * 16 + (L & 15));
            #pragma unroll
            for (int j = 0; j < 8; ++j) wf[wb][p][j] = sp[j * 64];
        }
    };
    auto packW = [&](int wb) {
        #pragma unroll
        for (int p = 0; p < 2; ++p) {
            unsigned hs[8];
            #pragma unroll
            for (int j = 0; j < 8; ++j) hs[j] = rtn_bf16(wf[wb][p][j]);
            wph[p].x = hs[0] | (hs[1] << 16); wph[p].y = hs[2] | (hs[3] << 16);
            wph[p].z = hs[4] | (hs[5] << 16); wph[p].w = hs[6] | (hs[7] << 16);
        }
    };
    auto storeW = [&]() {
        #pragma unroll
        for (int p = 0; p < 2; ++p)
            *(uint4*)(wbuf + (size_t)(2 * w + p) * 1024 + (size_t)L * 16) = wph[p];
    };
    auto bfrag = [&](int s2, int cf) -> short8 {
        return *(const short8*)(wbuf + (size_t)(s2 * 4 + cf) * 1024
                                     + (size_t)L * 16);
    };

    loadWf(0, csrc(0));
    loadWf(1, csrc(1));
    packW(0);

    float4v acc1[2][4];
    #pragma unroll
    for (int rt = 0; rt < 2; ++rt)
        #pragma unroll
        for (int cf = 0; cf < 4; ++cf) acc1[rt][cf] = (float4v)0.f;

    // ---------------- GEMM1: 20 chunks of K=64 ----------------
    for (int dt = 0; dt < 5; ++dt) {
        #pragma unroll
        for (int kk = 0; kk < 4; ++kk) {
            const int c = dt * 4 + kk;
            __syncthreads();          // prev chunk's B-reads done
            storeW();                 // chunk c images
            __syncthreads();          // images visible

            loadWf(c & 1, csrc(c + 2));   // refill freed wf buffer

            const int okk = (kk == 0) ? o0 : ((kk == 1) ? o1 : ((kk == 2) ? o2 : o3));
            const int off = dt * NDXT + okk;

            short8 ah[2][2];
            #pragma unroll
            for (int s2 = 0; s2 < 2; ++s2)
                #pragma unroll
                for (int rt = 0; rt < 2; ++rt)
                    ah[s2][rt] = *(const short8*)(xhrow[rt] + off + s2 * 32 + dseg);

            #pragma unroll
            for (int s2 = 0; s2 < 2; ++s2)
                #pragma unroll
                for (int cf = 0; cf < 4; ++cf) {
                    short8 bh = bfrag(s2, cf);
                    #pragma unroll
                    for (int rt = 0; rt < 2; ++rt)
                        acc1[rt][cf] = __builtin_amdgcn_mfma_f32_16x16x32_bf16(ah[s2][rt], bh, acc1[rt][cf], 0, 0, 0);
                }
            packW((c + 1) & 1);       // chunk c+1 (loaded at c-1: full cover)
        }
    }

    // ---------------- h1 -> bf16 himg; stage W2; GEMM2 ----------------------
    __syncthreads();
    storeW();                         // W2 images
    #pragma unroll
    for (int cf = 0; cf < 4; ++cf) {
        float bv = b1[(size_t)ne * H_ + cf * 16 + ccol];
        #pragma unroll
        for (int rt = 0; rt < 2; ++rt)
            #pragma unroll
            for (int reg = 0; reg < 4; ++reg) {
                float hv = fmaxf(acc1[rt][cf][reg] + bv, 0.f);
                himg[(w * 32 + rt * 16 + qrow + reg) * 72 + cf * 16 + ccol] =
                    (short)rtn_bf16(hv);
            }
    }
    __syncthreads();

    float4v acc2[2][4];
    #pragma unroll
    for (int rt = 0; rt < 2; ++rt)
        #pragma unroll
        for (int cf = 0; cf < 4; ++cf) acc2[rt][cf] = (float4v)0.f;
    #pragma unroll
    for (int s2 = 0; s2 < 2; ++s2) {
        short8 ha[2];
        #pragma unroll
        for (int rt = 0; rt < 2; ++rt)
            ha[rt] = *(const short8*)&himg[(w * 32 + rt * 16 + lrow) * 72 + s2 * 32 + dseg];
        #pragma unroll
        for (int cf = 0; cf < 4; ++cf) {
            short8 bh = bfrag(s2, cf);
            #pragma unroll
            for (int rt = 0; rt < 2; ++rt)
                acc2[rt][cf] = __builtin_amdgcn_mfma_f32_16x16x32_bf16(ha[rt], bh, acc2[rt][cf], 0, 0, 0);
        }
    }
    packW(1);                         // W3 (loaded at c=19)

    // ---------------- h2 -> bf16 himg; stage W3; GEMM3 ----------------------
    __syncthreads();
    storeW();                         // W3 images
    #pragma unroll
    for (int cf = 0; cf < 4; ++cf) {
        float bv = b2[(size_t)ne * H_ + cf * 16 + ccol];
        #pragma unroll
        for (int rt = 0; rt < 2; ++rt)
            #pragma unroll
            for (int reg = 0; reg < 4; ++reg) {
                float hv = fmaxf(acc2[rt][cf][reg] + bv, 0.f);
                himg[(w * 32 + rt * 16 + qrow + reg) * 72 + cf * 16 + ccol] =
                    (short)rtn_bf16(hv);
            }
    }
    __syncthreads();

    float4v acc3[2][4];
    #pragma unroll
    for (int rt = 0; rt < 2; ++rt)
        #pragma unroll
        for (int cf = 0; cf < 4; ++cf) acc3[rt][cf] = (float4v)0.f;
    #pragma unroll
    for (int s2 = 0; s2 < 2; ++s2) {
        short8 ha[2];
        #pragma unroll
        for (int rt = 0; rt < 2; ++rt)
            ha[rt] = *(const short8*)&himg[(w * 32 + rt * 16 + lrow) * 72 + s2 * 32 + dseg];
        #pragma unroll
        for (int cf = 0; cf < 4; ++cf) {
            short8 bh = bfrag(s2, cf);
            #pragma unroll
            for (int rt = 0; rt < 2; ++rt)
                acc3[rt][cf] = __builtin_amdgcn_mfma_f32_16x16x32_bf16(ha[rt], bh, acc3[rt][cf], 0, 0, 0);
        }
    }

    // ---------------- err epilogue (skip the 128 fix cells) -----------------
    {
        float b3v[4];
        #pragma unroll
        for (int cf = 0; cf < 4; ++cf) b3v[cf] = b3[(size_t)ne * D_ + cf * 16 + ccol];

        #pragma unroll
        for (int rt = 0; rt < 2; ++rt) {
            #pragma unroll
            for (int reg = 0; reg < 4; ++reg) {
                const int m  = rowbase + rt * 16 + qrow + reg;
                const int mc = m < M_ ? m : M_ - 1;
                const int b = mc / TW, t = mc % TW;
                const float* yp = x + ((size_t)(b * T_ + t + 2) * N_ + n) * D_;
                float s = 0.f;
                #pragma unroll
                for (int cf = 0; cf < 4; ++cf) {
                    float d = acc3[rt][cf][reg] + b3v[cf] - yp[cf * 16 + ccol];
                    s += d * d;
                }
                s += __shfl_xor(s, 1);
                s += __shfl_xor(s, 2);
                s += __shfl_xor(s, 4);
                s += __shfl_xor(s, 8);
                if (ccol == 0 && m < M_ && !(n == N_ - 1 && t == TW - 1)) {
                    err_ws[((size_t)m * N_ + n) * E_ + e] = s * (1.f / 64.f);
                }
            }
        }
    }
}

// ---------------------------------------------------------------------------
// Dispatch 3: reduce, 82 blocks x 256; per-block tree + one atomicAdd
// (out[0] zeroed in pre_kernel; stream-ordered).
__global__ __launch_bounds__(256) void moe_reduce_kernel(
    const float* __restrict__ err_ws, float* __restrict__ out)
{
    const int tid = threadIdx.x;
    const int idx = blockIdx.x * 256 + tid;
    float v = 0.f;
    if (idx < M_ * N_) {
        const int m = idx / N_, n = idx % N_;
        const float* ep = err_ws + (size_t)idx * E_;
        float ev[E_];
        float4 e0 = *(const float4*)ep;
        float4 e1 = *(const float4*)(ep + 4);
        ev[0] = e0.x; ev[1] = e0.y; ev[2] = e0.z; ev[3] = e0.w;
        ev[4] = e1.x; ev[5] = e1.y; ev[6] = e1.z; ev[7] = e1.w;
        float mn = ev[0];
        int am = 0;
        #pragma unroll
        for (int i = 1; i < E_; ++i) {
            if (ev[i] < mn) { mn = ev[i]; am = i; }
        }
        float p[E_];
        float Z = 0.f;
        #pragma unroll
        for (int i = 0; i < E_; ++i) { p[i] = expf(mn - ev[i]); Z += p[i]; }
        const float invZ = 1.f / Z;
        float kl = 0.f;
        #pragma unroll
        for (int i = 0; i < E_; ++i) {
            float q = p[i] * invZ;
            kl += q * (logf(q + 1e-9f) + 2.0794415416798357f);  // log(8)
        }
        v = mn + 0.01f * kl;
        const int t = m % TW, b = m / TW;
        if (t == TW - 1 && n == N_ - 1) out[1 + b] = (float)am;
    }
    __shared__ float sd[256];
    sd[tid] = v;
    __syncthreads();
    for (int s = 128; s > 0; s >>= 1) {
        if (tid < s) sd[tid] += sd[tid + s];
        __syncthreads();
    }
    if (tid == 0) atomicAdd(out, sd[0] * (1.f / 20160.f));  // / B / (N-1) / (T-4)
}

extern "C" void kernel_launch(void* const* d_in, const int* in_sizes, int n_in,
                              void* d_out, int out_size, void* d_ws, size_t ws_size,
                              hipStream_t stream)
{
    const float* x  = (const float*)d_in[0];
    const int*   nb = (const int*)d_in[1];
    const float* W1 = (const float*)d_in[2];
    const float* b1 = (const float*)d_in[3];
    const float* W2 = (const float*)d_in[4];
    const float* b2 = (const float*)d_in[5];
    const float* W3 = (const float*)d_in[6];
    const float* b3 = (const float*)d_in[7];
    float* out    = (float*)d_out;
    float* err_ws = (float*)d_ws;
    short* xh     = (short*)((char*)d_ws + XH_OFF);

    hipLaunchKernelGGL(pre_kernel, dim3(GRID), dim3(256), 0, stream,
                       x, nb, W1, b1, W2, b2, W3, b3, err_ws, xh, out);
    hipLaunchKernelGGL(moe_err_kernel, dim3(GRID), dim3(256), 0, stream,
                       x, xh, nb, W1, W2, W3, b1, b2, b3, err_ws);
    const int nred = (M_ * N_ + 255) / 256;
    hipLaunchKernelGGL(moe_reduce_kernel, dim3(nred), dim3(256), 0, stream, err_ws, out);
}

// Round 15
// 204.572 us; speedup vs baseline: 1.6415x; 1.6415x over previous
//
#include <hip/hip_runtime.h>
#include <math.h>

// Problem constants
#define B_   16
#define T_   64
#define N_   22
#define D_   64
#define K_   4
#define E_   8
#define H_   64
#define TW   59                 // valid time steps per batch (t=2..60 absolute)
#define M_   (B_ * TW)          // 944
#define NE_  (N_ * E_)          // 176
#define GRID (NE_ * 8)          // 1408
#define NDXT (N_ * D_)          // 1408
#define XTOT (B_ * T_ * N_ * D_)   // 1,441,792
#define NF4  (XTOT / 4)            // 360,448 float4s

typedef __attribute__((ext_vector_type(8))) short short8;
typedef __attribute__((ext_vector_type(4))) float float4v;

// workspace layout
#define ERRWS_BYTES  ((size_t)(M_ * N_ * E_) * 4)          // 664,576
#define XH_OFF       (ERRWS_BYTES)

// round-to-nearest bf16 (with tie bit): unbiased.
__device__ inline unsigned rtn_bf16(float f) {
    unsigned u = __float_as_uint(f);
    return (u + 0x7fffu + ((u >> 16) & 1u)) >> 16;
}

// ---------------------------------------------------------------------------
// Dispatch 1: blocks 0..127 = exact fp32 fix for the 128 expert_idx cells
// (b=g>>3, e=g&7 at t=TW-1, n=N-1); blocks 128..1407 = x -> bf16 RTN image;
// block 0 zeroes out[0] (for reduce's atomicAdd). [R13-proven code]
__global__ __launch_bounds__(256) void pre_kernel(
    const float* __restrict__ x, const int* __restrict__ nb,
    const float* __restrict__ W1, const float* __restrict__ b1,
    const float* __restrict__ W2, const float* __restrict__ b2,
    const float* __restrict__ W3, const float* __restrict__ b3,
    float* __restrict__ err_ws, short* __restrict__ xh,
    float* __restrict__ out)
{
    const int g   = blockIdx.x;
    const int tid = threadIdx.x;
    __shared__ __align__(16) char smem[6656];

    if (g < 128) {
        const int b = g >> 3;
        const int e = g & 7;
        const int n = N_ - 1, t = TW - 1;
        const int ne = n * E_ + e;
        const int j = tid & 63;
        const int q = tid >> 6;   // 0..3 K-quarter

        float* fbuf = (float*)smem;                      // 5120 B
        float (*part)[64] = (float(*)[64])(smem + 5120); // 1024 B
        float* h1s = (float*)(smem + 6144);              // 256 B
        float* h2s = (float*)(smem + 6400);              // 256 B

        if (g == 0 && tid == 0) out[0] = 0.f;

        for (int i = tid; i < 1280; i += 256) {
            int dt = i >> 8, r = i & 255;
            int k = r >> 6, d = r & 63;
            int nk = nb[n * K_ + k];
            fbuf[i] = x[(((size_t)(b * T_ + t + dt)) * N_ + nk) * D_ + d];
        }
        __syncthreads();

        const float* W1p = W1 + (size_t)ne * 1280 * 64;
        float s = 0.f;
        #pragma unroll 8
        for (int k = q * 320; k < q * 320 + 320; ++k) s += fbuf[k] * W1p[(size_t)k * 64 + j];
        part[q][j] = s;
        __syncthreads();
        if (q == 0)
            h1s[j] = fmaxf(part[0][j] + part[1][j] + part[2][j] + part[3][j]
                           + b1[(size_t)ne * H_ + j], 0.f);
        __syncthreads();

        const float* W2p = W2 + (size_t)ne * 4096;
        s = 0.f;
        #pragma unroll
        for (int k = q * 16; k < q * 16 + 16; ++k) s += h1s[k] * W2p[k * 64 + j];
        part[q][j] = s;
        __syncthreads();
        if (q == 0)
            h2s[j] = fmaxf(part[0][j] + part[1][j] + part[2][j] + part[3][j]
                           + b2[(size_t)ne * H_ + j], 0.f);
        __syncthreads();

        const float* W3p = W3 + (size_t)ne * 4096;
        s = 0.f;
        #pragma unroll
        for (int k = q * 16; k < q * 16 + 16; ++k) s += h2s[k] * W3p[k * 64 + j];
        part[q][j] = s;
        __syncthreads();
        if (q == 0) {
            float pred = part[0][j] + part[1][j] + part[2][j] + part[3][j]
                       + b3[(size_t)ne * D_ + j];
            float y = x[(((size_t)(b * T_ + t + 2)) * N_ + n) * D_ + j];
            float d = pred - y;
            float sq = d * d;
            sq += __shfl_xor(sq, 1);
            sq += __shfl_xor(sq, 2);
            sq += __shfl_xor(sq, 4);
            sq += __shfl_xor(sq, 8);
            sq += __shfl_xor(sq, 16);
            sq += __shfl_xor(sq, 32);
            if (j == 0) {
                int m = b * TW + t;
                err_ws[((size_t)m * N_ + n) * E_ + e] = sq * (1.f / 64.f);
            }
        }
    } else {
        int base = (g - 128) * 256 + tid;
        #pragma unroll
        for (int it = 0; it < 2; ++it) {
            int i = base + it * (1280 * 256);
            if (i < NF4) {
                float4 v = *(const float4*)(x + (size_t)i * 4);
                uint2 hp;
                hp.x = rtn_bf16(v.x) | (rtn_bf16(v.y) << 16);
                hp.y = rtn_bf16(v.z) | (rtn_bf16(v.w) << 16);
                *(uint2*)(xh + (size_t)i * 4) = hp;
            }
        }
    }
}

// ---------------------------------------------------------------------------
// Dispatch 2: GEMM, R11's exact 97 us body. (256,4): VGPR cap 128 -> compiler
// lands at 64, NO spill (R14 lesson: (256,6) forced VGPR to 40 -> 324 MB of
// scratch traffic, 2.3x slower). LDS 26,624 B allows up to 6 blocks/CU at
// the scheduler's discretion. Epilogue skips the 128 pre-computed fix cells.
__global__ __launch_bounds__(256, 4) void moe_err_kernel(
    const float* __restrict__ x, const short* __restrict__ xh,
    const int* __restrict__ nb,
    const float* __restrict__ W1, const float* __restrict__ W2,
    const float* __restrict__ W3,
    const float* __restrict__ b1, const float* __restrict__ b2,
    const float* __restrict__ b3, float* __restrict__ err_ws)
{
    const int tid = threadIdx.x;
    const int w   = tid >> 6;
    const int L   = tid & 63;
    const int g   = blockIdx.x;
    const int e   = g & 7;            // XCD = e
    const int mt  = (g >> 3) & 7;
    const int n   = g >> 6;
    const int ne  = n * E_ + e;

    __shared__ __align__(16) char smem[26624];
    char*  wbuf = smem;                       // 8 KB: 8 W images x 1 KB
    short* himg = (short*)(smem + 8192);      // 18,432 B: 128 x 72 shorts

    const int lrow = L & 15;
    const int dseg = (L >> 4) * 8;
    const int ccol = L & 15;
    const int qrow = (L >> 4) * 4;
    const int rowbase = mt * 128 + w * 32;

    const short* xhrow[2];
    #pragma unroll
    for (int rt = 0; rt < 2; ++rt) {
        int m  = rowbase + rt * 16 + lrow;
        int mc = m < M_ ? m : M_ - 1;
        int b = mc / TW, t = mc % TW;
        xhrow[rt] = xh + (size_t)(b * T_ + t) * NDXT;
    }

    const int o0 = __builtin_amdgcn_readfirstlane(nb[n * K_ + 0]) * D_;
    const int o1 = __builtin_amdgcn_readfirstlane(nb[n * K_ + 1]) * D_;
    const int o2 = __builtin_amdgcn_readfirstlane(nb[n * K_ + 2]) * D_;
    const int o3 = __builtin_amdgcn_readfirstlane(nb[n * K_ + 3]) * D_;

    const float* W1ne = W1 + (size_t)ne * (1280 * 64);
    const float* W2ne = W2 + (size_t)ne * 4096;
    const float* W3ne = W3 + (size_t)ne * 4096;
    auto csrc = [&](int c) {
        return c < 20 ? (W1ne + (size_t)c * 4096) : (c == 20 ? W2ne : W3ne);
    };

    // ---- W pipeline: 2-deep register prefetch; wave w owns images 2w,2w+1 ----
    float wf[2][2][8];
    uint4 wph[2];
    auto loadWf = [&](int wb, const float* src) {
        #pragma unroll
        for (int p = 0; p < 2; ++p) {
            const int pi = 2 * w + p;
            const float* sp = src + ((pi >> 2) * 32 + (L >> 4) * 8) * 64
                                  + ((pi & 3) * 16 + (L & 15));
            #pragma unroll
            for (int j = 0; j < 8; ++j) wf[wb][p][j] = sp[j * 64];
        }
    };
    auto packW = [&](int wb) {
        #pragma unroll
        for (int p = 0; p < 2; ++p) {
            unsigned hs[8];
            #pragma unroll
            for (int j = 0; j < 8; ++j) hs[j] = rtn_bf16(wf[wb][p][j]);
            wph[p].x = hs[0] | (hs[1] << 16); wph[p].y = hs[2] | (hs[3] << 16);
            wph[p].z = hs[4] | (hs[5] << 16); wph[p].w = hs[6] | (hs[7] << 16);
        }
    };
    auto storeW = [&]() {
        #pragma unroll
        for (int p = 0; p < 2; ++p)
            *(uint4*)(wbuf + (size_t)(2 * w + p) * 1024 + (size_t)L * 16) = wph[p];
    };
    auto bfrag = [&](int s2, int cf) -> short8 {
        return *(const short8*)(wbuf + (size_t)(s2 * 4 + cf) * 1024
                                     + (size_t)L * 16);
    };

    loadWf(0, csrc(0));
    loadWf(1, csrc(1));
    packW(0);

    float4v acc1[2][4];
    #pragma unroll
    for (int rt = 0; rt < 2; ++rt)
        #pragma unroll
        for (int cf = 0; cf < 4; ++cf) acc1[rt][cf] = (float4v)0.f;

    // ---------------- GEMM1: 20 chunks of K=64 ----------------
    for (int dt = 0; dt < 5; ++dt) {
        #pragma unroll
        for (int kk = 0; kk < 4; ++kk) {
            const int c = dt * 4 + kk;
            __syncthreads();          // prev chunk's B-reads done
            storeW();                 // chunk c images
            __syncthreads();          // images visible

            loadWf(c & 1, csrc(c + 2));   // refill freed wf buffer

            const int okk = (kk == 0) ? o0 : ((kk == 1) ? o1 : ((kk == 2) ? o2 : o3));
            const int off = dt * NDXT + okk;

            short8 ah[2][2];
            #pragma unroll
            for (int s2 = 0; s2 < 2; ++s2)
                #pragma unroll
                for (int rt = 0; rt < 2; ++rt)
                    ah[s2][rt] = *(const short8*)(xhrow[rt] + off + s2 * 32 + dseg);

            #pragma unroll
            for (int s2 = 0; s2 < 2; ++s2)
                #pragma unroll
                for (int cf = 0; cf < 4; ++cf) {
                    short8 bh = bfrag(s2, cf);
                    #pragma unroll
                    for (int rt = 0; rt < 2; ++rt)
                        acc1[rt][cf] = __builtin_amdgcn_mfma_f32_16x16x32_bf16(ah[s2][rt], bh, acc1[rt][cf], 0, 0, 0);
                }
            packW((c + 1) & 1);       // chunk c+1 (loaded at c-1: full cover)
        }
    }

    // ---------------- h1 -> bf16 himg; stage W2; GEMM2 ----------------------
    __syncthreads();
    storeW();                         // W2 images
    #pragma unroll
    for (int cf = 0; cf < 4; ++cf) {
        float bv = b1[(size_t)ne * H_ + cf * 16 + ccol];
        #pragma unroll
        for (int rt = 0; rt < 2; ++rt)
            #pragma unroll
            for (int reg = 0; reg < 4; ++reg) {
                float hv = fmaxf(acc1[rt][cf][reg] + bv, 0.f);
                himg[(w * 32 + rt * 16 + qrow + reg) * 72 + cf * 16 + ccol] =
                    (short)rtn_bf16(hv);
            }
    }
    __syncthreads();

    float4v acc2[2][4];
    #pragma unroll
    for (int rt = 0; rt < 2; ++rt)
        #pragma unroll
        for (int cf = 0; cf < 4; ++cf) acc2[rt][cf] = (float4v)0.f;
    #pragma unroll
    for (int s2 = 0; s2 < 2; ++s2) {
        short8 ha[2];
        #pragma unroll
        for (int rt = 0; rt < 2; ++rt)
            ha[rt] = *(const short8*)&himg[(w * 32 + rt * 16 + lrow) * 72 + s2 * 32 + dseg];
        #pragma unroll
        for (int cf = 0; cf < 4; ++cf) {
            short8 bh = bfrag(s2, cf);
            #pragma unroll
            for (int rt = 0; rt < 2; ++rt)
                acc2[rt][cf] = __builtin_amdgcn_mfma_f32_16x16x32_bf16(ha[rt], bh, acc2[rt][cf], 0, 0, 0);
        }
    }
    packW(1);                         // W3 (loaded at c=19)

    // ---------------- h2 -> bf16 himg; stage W3; GEMM3 ----------------------
    __syncthreads();
    storeW();                         // W3 images
    #pragma unroll
    for (int cf = 0; cf < 4; ++cf) {
        float bv = b2[(size_t)ne * H_ + cf * 16 + ccol];
        #pragma unroll
        for (int rt = 0; rt < 2; ++rt)
            #pragma unroll
            for (int reg = 0; reg < 4; ++reg) {
                float hv = fmaxf(acc2[rt][cf][reg] + bv, 0.f);
                himg[(w * 32 + rt * 16 + qrow + reg) * 72 + cf * 16 + ccol] =
                    (short)rtn_bf16(hv);
            }
    }
    __syncthreads();

    float4v acc3[2][4];
    #pragma unroll
    for (int rt = 0; rt < 2; ++rt)
        #pragma unroll
        for (int cf = 0; cf < 4; ++cf) acc3[rt][cf] = (float4v)0.f;
    #pragma unroll
    for (int s2 = 0; s2 < 2; ++s2) {
        short8 ha[2];
        #pragma unroll
        for (int rt = 0; rt < 2; ++rt)
            ha[rt] = *(const short8*)&himg[(w * 32 + rt * 16 + lrow) * 72 + s2 * 32 + dseg];
        #pragma unroll
        for (int cf = 0; cf < 4; ++cf) {
            short8 bh = bfrag(s2, cf);
            #pragma unroll
            for (int rt = 0; rt < 2; ++rt)
                acc3[rt][cf] = __builtin_amdgcn_mfma_f32_16x16x32_bf16(ha[rt], bh, acc3[rt][cf], 0, 0, 0);
        }
    }

    // ---------------- err epilogue (skip the 128 fix cells) -----------------
    {
        float b3v[4];
        #pragma unroll
        for (int cf = 0; cf < 4; ++cf) b3v[cf] = b3[(size_t)ne * D_ + cf * 16 + ccol];

        #pragma unroll
        for (int rt = 0; rt < 2; ++rt) {
            #pragma unroll
            for (int reg = 0; reg < 4; ++reg) {
                const int m  = rowbase + rt * 16 + qrow + reg;
                const int mc = m < M_ ? m : M_ - 1;
                const int b = mc / TW, t = mc % TW;
                const float* yp = x + ((size_t)(b * T_ + t + 2) * N_ + n) * D_;
                float s = 0.f;
                #pragma unroll
                for (int cf = 0; cf < 4; ++cf) {
                    float d = acc3[rt][cf][reg] + b3v[cf] - yp[cf * 16 + ccol];
                    s += d * d;
                }
                s += __shfl_xor(s, 1);
                s += __shfl_xor(s, 2);
                s += __shfl_xor(s, 4);
                s += __shfl_xor(s, 8);
                if (ccol == 0 && m < M_ && !(n == N_ - 1 && t == TW - 1)) {
                    err_ws[((size_t)m * N_ + n) * E_ + e] = s * (1.f / 64.f);
                }
            }
        }
    }
}

// ---------------------------------------------------------------------------
// Dispatch 3: reduce, 82 blocks x 256; per-block tree + one atomicAdd
// (out[0] zeroed in pre_kernel; stream-ordered).
__global__ __launch_bounds__(256) void moe_reduce_kernel(
    const float* __restrict__ err_ws, float* __restrict__ out)
{
    const int tid = threadIdx.x;
    const int idx = blockIdx.x * 256 + tid;
    float v = 0.f;
    if (idx < M_ * N_) {
        const int m = idx / N_, n = idx % N_;
        const float* ep = err_ws + (size_t)idx * E_;
        float ev[E_];
        float4 e0 = *(const float4*)ep;
        float4 e1 = *(const float4*)(ep + 4);
        ev[0] = e0.x; ev[1] = e0.y; ev[2] = e0.z; ev[3] = e0.w;
        ev[4] = e1.x; ev[5] = e1.y; ev[6] = e1.z; ev[7] = e1.w;
        float mn = ev[0];
        int am = 0;
        #pragma unroll
        for (int i = 1; i < E_; ++i) {
            if (ev[i] < mn) { mn = ev[i]; am = i; }
        }
        float p[E_];
        float Z = 0.f;
        #pragma unroll
        for (int i = 0; i < E_; ++i) { p[i] = expf(mn - ev[i]); Z += p[i]; }
        const float invZ = 1.f / Z;
        float kl = 0.f;
        #pragma unroll
        for (int i = 0; i < E_; ++i) {
            float q = p[i] * invZ;
            kl += q * (logf(q + 1e-9f) + 2.0794415416798357f);  // log(8)
        }
        v = mn + 0.01f * kl;
        const int t = m % TW, b = m / TW;
        if (t == TW - 1 && n == N_ - 1) out[1 + b] = (float)am;
    }
    __shared__ float sd[256];
    sd[tid] = v;
    __syncthreads();
    for (int s = 128; s > 0; s >>= 1) {
        if (tid < s) sd[tid] += sd[tid + s];
        __syncthreads();
    }
    if (tid == 0) atomicAdd(out, sd[0] * (1.f / 20160.f));  // / B / (N-1) / (T-4)
}

extern "C" void kernel_launch(void* const* d_in, const int* in_sizes, int n_in,
                              void* d_out, int out_size, void* d_ws, size_t ws_size,
                              hipStream_t stream)
{
    const float* x  = (const float*)d_in[0];
    const int*   nb = (const int*)d_in[1];
    const float* W1 = (const float*)d_in[2];
    const float* b1 = (const float*)d_in[3];
    const float* W2 = (const float*)d_in[4];
    const float* b2 = (const float*)d_in[5];
    const float* W3 = (const float*)d_in[6];
    const float* b3 = (const float*)d_in[7];
    float* out    = (float*)d_out;
    float* err_ws = (float*)d_ws;
    short* xh     = (short*)((char*)d_ws + XH_OFF);

    hipLaunchKernelGGL(pre_kernel, dim3(GRID), dim3(256), 0, stream,
                       x, nb, W1, b1, W2, b2, W3, b3, err_ws, xh, out);
    hipLaunchKernelGGL(moe_err_kernel, dim3(GRID), dim3(256), 0, stream,
                       x, xh, nb, W1, W2, W3, b1, b2, b3, err_ws);
    const int nred = (M_ * N_ + 255) / 256;
    hipLaunchKernelGGL(moe_reduce_kernel, dim3(nred), dim3(256), 0, stream, err_ws, out);
}